// Round 7
// baseline (32.743 us; speedup 1.0000x reference)
//
#include <hip/hip_runtime.h>

// TransformerBlockQuantum: B=16384, S=8, E=8, H=8 (dk=1), NW=8, FFN=512.
// R7: 32 tokens per wave (4096 single-wave blocks -> 16 waves/CU, was 8).
//   Front per-lane as before; lanes 32-63 mirror lanes 0-31 (masked writes).
//   FFN via v_mfma_f32_16x16x16_f16: A1 (W1+bias row) resident in 64 regs,
//   A2 (W2) STREAMED from L2 in-loop with 4-deep prefetch; A2 rows m>=8 are
//   garbage but only pollute D2 rows 8-15 which are never read.
//   One fused loop: 2 token-groups (16 each) = 2 independent MFMA acc chains.

typedef __fp16 half2v __attribute__((ext_vector_type(2)));
typedef __fp16 half4  __attribute__((ext_vector_type(4)));
typedef float  float4v __attribute__((ext_vector_type(4)));

#define SWZ(v, J) __int_as_float(__builtin_amdgcn_ds_swizzle(__float_as_int(v), ((J) << 5) | 0x18))

__global__ __launch_bounds__(64) void tbq_fused(
    const float* __restrict__ x,
    const float* __restrict__ ipw, const float* __restrict__ ipb,
    const float* __restrict__ opw, const float* __restrict__ opb,
    const float* __restrict__ rxa,
    const float* __restrict__ cw,  const float* __restrict__ cb,
    const float* __restrict__ g1,  const float* __restrict__ b1,
    const float* __restrict__ rxf,
    const float* __restrict__ l1w, const float* __restrict__ l1b,
    const float* __restrict__ l2w, const float* __restrict__ l2b,
    const float* __restrict__ g2,  const float* __restrict__ b2,
    float* __restrict__ out)
{
    __shared__ half4 lds_zf[32][2];     // zf^T staging, 16B/token
    __shared__ float lds_f[32 * 10];    // ffn_out roundtrip, stride 10 floats

    const int l      = threadIdx.x;
    const int lane32 = l & 31;
    const int tok    = blockIdx.x * 32 + lane32;   // lanes 32-63 mirror
    const int base   = tok * 8;
    const int m      = l & 15;
    const int k0     = (l >> 4) * 4;               // 0,4,8,12

    // ---- front (per-lane token) ----
    float xr[8];
    {
        const float4* px = reinterpret_cast<const float4*>(x + base);
        float4 a = px[0], b = px[1];
        xr[0] = a.x; xr[1] = a.y; xr[2] = a.z; xr[3] = a.w;
        xr[4] = b.x; xr[5] = b.y; xr[6] = b.z; xr[7] = b.w;
    }

    float q[8], k[8], v[8];
    #pragma unroll
    for (int e = 0; e < 8; ++e) {
        float aq = ipb[e], ak = ipb[8 + e], av = ipb[16 + e];
        #pragma unroll
        for (int d = 0; d < 8; ++d) {
            aq = fmaf(xr[d], ipw[e * 8 + d],       aq);
            ak = fmaf(xr[d], ipw[64 + e * 8 + d],  ak);
            av = fmaf(xr[d], ipw[128 + e * 8 + d], av);
        }
        q[e] = aq; k[e] = ak; v[e] = av;
    }

    float orow[8];
    #pragma unroll
    for (int h = 0; h < 8; ++h) {
        const float kh = k[h], vh = v[h], qh = q[h];
        float kk[8], vv[8];
        kk[0] = SWZ(kh, 0); kk[1] = SWZ(kh, 1); kk[2] = SWZ(kh, 2); kk[3] = SWZ(kh, 3);
        kk[4] = SWZ(kh, 4); kk[5] = SWZ(kh, 5); kk[6] = SWZ(kh, 6); kk[7] = SWZ(kh, 7);
        vv[0] = SWZ(vh, 0); vv[1] = SWZ(vh, 1); vv[2] = SWZ(vh, 2); vv[3] = SWZ(vh, 3);
        vv[4] = SWZ(vh, 4); vv[5] = SWZ(vh, 5); vv[6] = SWZ(vh, 6); vv[7] = SWZ(vh, 7);
        float sc[8];
        #pragma unroll
        for (int j = 0; j < 8; ++j) sc[j] = qh * kk[j];
        float mx = fmaxf(fmaxf(fmaxf(sc[0], sc[1]), fmaxf(sc[2], sc[3])),
                         fmaxf(fmaxf(sc[4], sc[5]), fmaxf(sc[6], sc[7])));
        float p[8];
        #pragma unroll
        for (int j = 0; j < 8; ++j) p[j] = __expf(sc[j] - mx);
        float sum = ((p[0] + p[1]) + (p[2] + p[3])) + ((p[4] + p[5]) + (p[6] + p[7]));
        float ov = 0.f;
        #pragma unroll
        for (int j = 0; j < 8; ++j) ov = fmaf(p[j], vv[j], ov);
        orow[h] = ov * __builtin_amdgcn_rcpf(sum);
    }

    // ---- gather A1 fragments here (L2-hot; latency hides under back half) ----
    // A-frag (16x16x16f16): lane l holds A[m][k0+j], j=0..3.
    // A1[nf]: f = nf*16+m; k<8 -> W1[f][k]; k==8 -> l1b[f]; else 0.
    half4 a1[32];
    const half4 zh = {(__fp16)0.f, (__fp16)0.f, (__fp16)0.f, (__fp16)0.f};
    if (l < 32) {                        // k0 = 0 or 4: W1 columns
        #pragma unroll
        for (int nf = 0; nf < 32; ++nf) {
            float4 w = *reinterpret_cast<const float4*>(l1w + (nf * 16 + m) * 8 + k0);
            half2v c0 = __builtin_amdgcn_cvt_pkrtz(w.x, w.y);
            half2v c1 = __builtin_amdgcn_cvt_pkrtz(w.z, w.w);
            half4 r; r.x = c0.x; r.y = c0.y; r.z = c1.x; r.w = c1.y;
            a1[nf] = r;
        }
    } else if (l < 48) {                 // k0 = 8: bias row at k==8
        #pragma unroll
        for (int nf = 0; nf < 32; ++nf) {
            half4 r = zh; r.x = (__fp16)l1b[nf * 16 + m];
            a1[nf] = r;
        }
    } else {                             // k0 = 12: zero pad
        #pragma unroll
        for (int nf = 0; nf < 32; ++nf) a1[nf] = zh;
    }

    // ---- out_proj, quantum ring, combine x2, LN1 ----
    float ao[8];
    #pragma unroll
    for (int e = 0; e < 8; ++e) {
        float t = opb[e];
        #pragma unroll
        for (int h = 0; h < 8; ++h) t = fmaf(orow[h], opw[e * 8 + h], t);
        ao[e] = t;
    }

    float c[8];
    #pragma unroll
    for (int w = 0; w < 8; ++w) c[w] = __cosf(ao[w] + rxa[w]);
    float z[8];
    {
        float run = c[0];
        #pragma unroll
        for (int w = 1; w < 8; ++w) { run *= c[w]; z[w] = run; }
        float s17 = c[1];
        #pragma unroll
        for (int w = 2; w < 8; ++w) s17 *= c[w];
        z[0] = s17;
    }

    float saq[8];
    #pragma unroll
    for (int e = 0; e < 8; ++e) {
        float t = cb[e];
        #pragma unroll
        for (int w = 0; w < 8; ++w) t = fmaf(z[w], cw[e * 8 + w], t);
        saq[e] = ao[e] + t;
    }
    float at[8];
    #pragma unroll
    for (int e = 0; e < 8; ++e) {
        float t = cb[e];
        #pragma unroll
        for (int w = 0; w < 8; ++w) t = fmaf(saq[w], cw[e * 8 + w], t);
        at[e] = t;
    }

    float hh[8];
    {
        float r[8]; float mean = 0.f;
        #pragma unroll
        for (int e = 0; e < 8; ++e) { r[e] = xr[e] + at[e]; mean += r[e]; }
        mean *= 0.125f;
        float var = 0.f;
        #pragma unroll
        for (int e = 0; e < 8; ++e) { float d = r[e] - mean; var = fmaf(d, d, var); }
        var *= 0.125f;
        float rs = __builtin_amdgcn_rsqf(var + 1e-5f);
        #pragma unroll
        for (int e = 0; e < 8; ++e) hh[e] = fmaf((r[e] - mean) * rs, g1[e], b1[e]);
    }

    // ---- zf = cos(h + rx_ffn), publish (lanes 0-31 only) ----
    {
        float zfv[8];
        #pragma unroll
        for (int w = 0; w < 8; ++w) zfv[w] = __cosf(hh[w] + rxf[w]);
        half2v p0 = __builtin_amdgcn_cvt_pkrtz(zfv[0], zfv[1]);
        half2v p1 = __builtin_amdgcn_cvt_pkrtz(zfv[2], zfv[3]);
        half2v p2 = __builtin_amdgcn_cvt_pkrtz(zfv[4], zfv[5]);
        half2v p3 = __builtin_amdgcn_cvt_pkrtz(zfv[6], zfv[7]);
        half4 lo, hi;
        lo.x = p0.x; lo.y = p0.y; lo.z = p1.x; lo.w = p1.y;
        hi.x = p2.x; hi.y = p2.y; hi.z = p3.x; hi.w = p3.y;
        if (l < 32) { lds_zf[lane32][0] = lo; lds_zf[lane32][1] = hi; }
    }
    __syncthreads();    // single-wave block: near-free

    // ---- FFN: 2 token-groups (16 each) in one unrolled loop; A2 streamed ----
    half4 bz0 = zh, bz1 = zh;
    if (l < 32) {
        bz0 = lds_zf[m][l >> 4];          // tokens 0-15
        bz1 = lds_zf[16 + m][l >> 4];     // tokens 16-31
    } else if (l < 48) {
        bz0.x = (__fp16)1.f; bz1.x = (__fp16)1.f;   // bias row k==8
    }

    const float4v zero4 = {0.f, 0.f, 0.f, 0.f};
    float4v acc0 = zero4, acc1 = zero4;

    // A2 stream: lane l -> W2[m][nf*16 + k0 .. +3]; rows m>=8 never loaded
    // (their D2 rows 8-15 are never read, garbage is row-local).
    float4 pf[4];
    #pragma unroll
    for (int i = 0; i < 4; ++i)
        if (m < 8) pf[i] = *reinterpret_cast<const float4*>(l2w + m * 512 + i * 16 + k0);

    #pragma unroll
    for (int nf = 0; nf < 32; ++nf) {
        float4 w = pf[nf & 3];
        if (nf < 28 && m < 8)
            pf[nf & 3] = *reinterpret_cast<const float4*>(l2w + m * 512 + (nf + 4) * 16 + k0);
        half2v c0 = __builtin_amdgcn_cvt_pkrtz(w.x, w.y);
        half2v c1 = __builtin_amdgcn_cvt_pkrtz(w.z, w.w);
        half4 a2f; a2f.x = c0.x; a2f.y = c0.y; a2f.z = c1.x; a2f.w = c1.y;

        float4v d0 = __builtin_amdgcn_mfma_f32_16x16x16f16(a1[nf], bz0, zero4, 0, 0, 0);
        float4v d1 = __builtin_amdgcn_mfma_f32_16x16x16f16(a1[nf], bz1, zero4, 0, 0, 0);
        d0.x = fmaxf(d0.x, 0.f); d0.y = fmaxf(d0.y, 0.f);
        d0.z = fmaxf(d0.z, 0.f); d0.w = fmaxf(d0.w, 0.f);
        d1.x = fmaxf(d1.x, 0.f); d1.y = fmaxf(d1.y, 0.f);
        d1.z = fmaxf(d1.z, 0.f); d1.w = fmaxf(d1.w, 0.f);
        half2v q00 = __builtin_amdgcn_cvt_pkrtz(d0.x, d0.y);
        half2v q01 = __builtin_amdgcn_cvt_pkrtz(d0.z, d0.w);
        half2v q10 = __builtin_amdgcn_cvt_pkrtz(d1.x, d1.y);
        half2v q11 = __builtin_amdgcn_cvt_pkrtz(d1.z, d1.w);
        half4 bu0; bu0.x = q00.x; bu0.y = q00.y; bu0.z = q01.x; bu0.w = q01.y;
        half4 bu1; bu1.x = q10.x; bu1.y = q10.y; bu1.z = q11.x; bu1.w = q11.y;
        acc0 = __builtin_amdgcn_mfma_f32_16x16x16f16(a2f, bu0, acc0, 0, 0, 0);
        acc1 = __builtin_amdgcn_mfma_f32_16x16x16f16(a2f, bu1, acc1, 0, 0, 0);
    }

    // D2 lane l (<32): ffn_out[tok = grp*16 + m][e = (l>>4)*4 + r]
    if (l < 32) {
        float* dst0 = &lds_f[(m) * 10 + (l >> 4) * 4];
        dst0[0] = acc0.x; dst0[1] = acc0.y; dst0[2] = acc0.z; dst0[3] = acc0.w;
        float* dst1 = &lds_f[(16 + m) * 10 + (l >> 4) * 4];
        dst1[0] = acc1.x; dst1[1] = acc1.y; dst1[2] = acc1.z; dst1[3] = acc1.w;
    }
    __syncthreads();

    // ---- residual + LN2 + store (lanes 0-31) ----
    if (l < 32) {
        float r2[8]; float mean2 = 0.f;
        #pragma unroll
        for (int e = 0; e < 8; ++e) {
            float fo = lds_f[lane32 * 10 + e] + l2b[e];
            r2[e] = hh[e] + fo;
            mean2 += r2[e];
        }
        mean2 *= 0.125f;
        float var2 = 0.f;
        #pragma unroll
        for (int e = 0; e < 8; ++e) { float d = r2[e] - mean2; var2 = fmaf(d, d, var2); }
        var2 *= 0.125f;
        float rs2 = __builtin_amdgcn_rsqf(var2 + 1e-5f);
        float o[8];
        #pragma unroll
        for (int e = 0; e < 8; ++e) o[e] = fmaf((r2[e] - mean2) * rs2, g2[e], b2[e]);

        float4* po = reinterpret_cast<float4*>(out + base);
        po[0] = make_float4(o[0], o[1], o[2], o[3]);
        po[1] = make_float4(o[4], o[5], o[6], o[7]);
    }
}

extern "C" void kernel_launch(void* const* d_in, const int* in_sizes, int n_in,
                              void* d_out, int out_size, void* d_ws, size_t ws_size,
                              hipStream_t stream) {
    const float* x   = (const float*)d_in[0];
    const float* ipw = (const float*)d_in[1];
    const float* ipb = (const float*)d_in[2];
    const float* opw = (const float*)d_in[3];
    const float* opb = (const float*)d_in[4];
    const float* rxa = (const float*)d_in[5];
    const float* cw  = (const float*)d_in[6];
    const float* cb  = (const float*)d_in[7];
    const float* g1  = (const float*)d_in[8];
    const float* b1  = (const float*)d_in[9];
    const float* rxf = (const float*)d_in[10];
    const float* l1w = (const float*)d_in[11];
    const float* l1b = (const float*)d_in[12];
    const float* l2w = (const float*)d_in[13];
    const float* l2b = (const float*)d_in[14];
    const float* g2  = (const float*)d_in[15];
    const float* b2  = (const float*)d_in[16];
    float* out = (float*)d_out;

    const int tokens = 16384 * 8;                       // 131072
    tbq_fused<<<dim3(tokens / 32), dim3(64), 0, stream>>>(
        x, ipw, ipb, opw, opb, rxa, cw, cb, g1, b1, rxf,
        l1w, l1b, l2w, l2b, g2, b2, out);
}